// Round 19
// baseline (268.440 us; speedup 1.0000x reference)
//
#include <hip/hip_runtime.h>

// Problem constants
#define NB 16
#define NH 64
#define NW 64
#define ND 128
#define NK 4096
#define NROWS (NB * NH * NW)        // 65536
#define OUT_ELEMS (NB * ND * NH * NW)  // 8388608
// fp16 single-term fast path: score-gap error sigma ~= 0.02; margin 0.10
// ~= 5 sigma. Exact-fp32 rescue handles everything below the margin.
// Ledger: R13 top-3 tracking = 2x argmin (VALU budget ~5 ops/score).
// R14 rescue bound by serialized plain-load staging. R15 dropped
// launch_bounds -> 64-VGPR spill (546MB scratch). R16/R18 pin restored:
// 267.7us, argmin 120us top. R19: out_kernel float4 loads (G13).
#define MARGIN_F 0.10f

typedef _Float16 f16x8 __attribute__((ext_vector_type(8)));
typedef float f32x4 __attribute__((ext_vector_type(4)));

__device__ __forceinline__ unsigned short f2h(float x) {
    _Float16 h = (_Float16)x;              // v_cvt_f16_f32, RNE
    return __builtin_bit_cast(unsigned short, h);
}
// Order-preserving (score,idx) packing: smaller score first, then smaller idx.
__device__ __forceinline__ unsigned long long pack_si(float s, int idx) {
    unsigned int u = __float_as_uint(s);
    unsigned int key = ((int)u < 0) ? ~u : (u | 0x80000000u);
    return ((unsigned long long)key << 32) | (unsigned int)idx;
}

// ---------------------------------------------------------------------------
// Kernel 1: emb prep — enorm (fp32 exact) + fp16 codebook e_h stored in a
// SWIZZLED layout: ushort index = code*128 + (dim ^ ((code&7)<<3)).
// ---------------------------------------------------------------------------
__global__ void emb_prep_kernel(const float* __restrict__ emb,
                                float* __restrict__ enorm,
                                unsigned short* __restrict__ e_h) {
    int wave = (blockIdx.x * blockDim.x + threadIdx.x) >> 6;
    int lane = threadIdx.x & 63;
    if (wave >= NK) return;
    const float* e = emb + (size_t)wave * ND;
    float a = e[lane];
    float b = e[lane + 64];
    const int m = (wave & 7) << 3;
    e_h[(size_t)wave * ND + (lane ^ m)] = f2h(a);
    e_h[(size_t)wave * ND + ((lane + 64) ^ m)] = f2h(b);
    float s = a * a + b * b;
#pragma unroll
    for (int off = 32; off > 0; off >>= 1) s += __shfl_down(s, off, 64);
    if (lane == 0) enorm[wave] = s;
}

// ---------------------------------------------------------------------------
// Kernel 1b: transpose codebook -> emb_t[d2][code] (float2 = dims 2d2,2d2+1).
// Enables LINEAR global_load_lds staging of per-chunk code tiles in rescue.
// ---------------------------------------------------------------------------
__global__ void transp_kernel(const float* __restrict__ emb,
                              float2* __restrict__ emb_t) {
    __shared__ float2 tile[64 * 65];
    const int cb = blockIdx.x * 64;
    const int t = threadIdx.x;
#pragma unroll
    for (int q = 0; q < 16; q++) {
        int i = t + 256 * q;        // 0..4095
        int code = i >> 6;
        int d2 = i & 63;
        tile[code * 65 + d2] = ((const float2*)(emb + (size_t)(cb + code) * ND))[d2];
    }
    __syncthreads();
#pragma unroll
    for (int q = 0; q < 16; q++) {
        int i = t + 256 * q;
        int d2 = i >> 6;
        int code = i & 63;
        emb_t[(size_t)d2 * NK + cb + code] = tile[code * 65 + d2];
    }
}

// ---------------------------------------------------------------------------
// Kernel 2: MFMA argmin (R11 verified version, unchanged — 120us measured).
// Max-form q = z.e - 0.5*en via acc-init fold; argmin s == argmax q;
// branch-free top-2 update (5 ops/score).
// ---------------------------------------------------------------------------
#define ZST 136   // z staging row stride in ushort (272 B)

__global__ void
__attribute__((amdgpu_flat_work_group_size(256, 256)))
mfma_argmin_kernel(const float* __restrict__ z,
                   const unsigned short* __restrict__ e_h,
                   const float* __restrict__ enorm,
                   int* __restrict__ idx_out,
                   int* __restrict__ rcount,
                   int* __restrict__ rlist,
                   unsigned long long* __restrict__ rpart) {
    __shared__ alignas(16) unsigned short ubuf[2 * 64 * ND];   // 32768 B
    __shared__ float redb1[2 * 64];
    __shared__ float redb2[2 * 64];
    __shared__ int   redi1[2 * 64];

    const int bid = blockIdx.x;
    const int rowbase = bid * 64;
    const int t = threadIdx.x;
    const int lane = t & 63;
    const int wid = __builtin_amdgcn_readfirstlane(t >> 6);

    const float4* zg = (const float4*)(z + (size_t)rowbase * ND);
#pragma unroll
    for (int q = 0; q < 8; q++) {
        int i = t + 256 * q;               // 0..2047
        float4 v = zg[i];
        int r = i >> 5;
        int c4 = (i & 31) << 2;
        ushort4 hv = make_ushort4(f2h(v.x), f2h(v.y), f2h(v.z), f2h(v.w));
        *(ushort4*)&ubuf[r * ZST + c4] = hv;
    }
    __syncthreads();

    const int quad = lane >> 4;
    const int c = lane & 15;
    const int rh = wid >> 1;               // row half
    const int ch = wid & 1;                // code half

    f16x8 ar[2][4];
#pragma unroll
    for (int mi = 0; mi < 2; mi++)
#pragma unroll
        for (int kk = 0; kk < 4; kk++)
            ar[mi][kk] = *(const f16x8*)&ubuf[(rh * 32 + mi * 16 + c) * ZST + quad * 8 + kk * 32];
    __syncthreads();

#pragma unroll
    for (int j = 0; j < 4; j++) {
        int seg = (wid << 2) + j;
        __builtin_amdgcn_global_load_lds(
            (const unsigned int*)(e_h + seg * 512 + lane * 8),
            (unsigned int*)&ubuf[seg * 512], 16, 0, 0);
    }
    float en0 = enorm[ch * 32 + c];
    float en1 = enorm[ch * 32 + 16 + c];
    __syncthreads();

    const int bswz = (c & 7) << 3;
    const int bbase0 = (ch * 32 + c) * ND;

    float b1[2][4], b2[2][4];
    int i1[2][4];
#pragma unroll
    for (int mi = 0; mi < 2; mi++)
#pragma unroll
        for (int r = 0; r < 4; r++) { b1[mi][r] = -3.4e38f; b2[mi][r] = -3.4e38f; i1[mi][r] = 0; }

    for (int ts = 0; ts < NK / 64; ts++) {
        const int cur = ts & 1;
        const int curoff = cur << 13;

        float nen0 = 0.f, nen1 = 0.f;
        if (ts < NK / 64 - 1) {
            nen0 = enorm[(ts + 1) * 64 + ch * 32 + c];
            nen1 = enorm[(ts + 1) * 64 + ch * 32 + 16 + c];
            const unsigned short* gt = e_h + (size_t)(ts + 1) * (64 * ND);
#pragma unroll
            for (int j = 0; j < 4; j++) {
                int seg = (wid << 2) + j;
                __builtin_amdgcn_global_load_lds(
                    (const unsigned int*)(gt + seg * 512 + lane * 8),
                    (unsigned int*)&ubuf[(curoff ^ 8192) + seg * 512], 16, 0, 0);
            }
        }

        const float h0 = -0.5f * en0;
        const float h1 = -0.5f * en1;
        f32x4 acc[2][2];
#pragma unroll
        for (int mi = 0; mi < 2; mi++) {
            acc[mi][0] = (f32x4){h0, h0, h0, h0};
            acc[mi][1] = (f32x4){h1, h1, h1, h1};
        }

#pragma unroll
        for (int kk = 0; kk < 4; kk++) {
            const int doff = (quad * 8 + kk * 32) ^ bswz;
            f16x8 bv0 = *(const f16x8*)&ubuf[curoff + bbase0 + doff];
            f16x8 bv1 = *(const f16x8*)&ubuf[curoff + bbase0 + 16 * ND + doff];
            acc[0][0] = __builtin_amdgcn_mfma_f32_16x16x32_f16(ar[0][kk], bv0, acc[0][0], 0, 0, 0);
            acc[0][1] = __builtin_amdgcn_mfma_f32_16x16x32_f16(ar[0][kk], bv1, acc[0][1], 0, 0, 0);
            acc[1][0] = __builtin_amdgcn_mfma_f32_16x16x32_f16(ar[1][kk], bv0, acc[1][0], 0, 0, 0);
            acc[1][1] = __builtin_amdgcn_mfma_f32_16x16x32_f16(ar[1][kk], bv1, acc[1][1], 0, 0, 0);
        }

#pragma unroll
        for (int ni = 0; ni < 2; ni++) {
            const int n = ts * 64 + ch * 32 + ni * 16 + c;
#pragma unroll
            for (int mi = 0; mi < 2; mi++)
#pragma unroll
                for (int r = 0; r < 4; r++) {
                    float q = acc[mi][ni][r];
                    b2[mi][r] = fmaxf(b2[mi][r], fminf(b1[mi][r], q));
                    i1[mi][r] = (q > b1[mi][r]) ? n : i1[mi][r];
                    b1[mi][r] = fmaxf(b1[mi][r], q);
                }
        }

        __syncthreads();
        en0 = nen0;
        en1 = nen1;
    }

#pragma unroll
    for (int off = 1; off < 16; off <<= 1) {
#pragma unroll
        for (int mi = 0; mi < 2; mi++)
#pragma unroll
            for (int r = 0; r < 4; r++) {
                float ob1 = __shfl_xor(b1[mi][r], off, 64);
                float ob2 = __shfl_xor(b2[mi][r], off, 64);
                int oi1 = __shfl_xor(i1[mi][r], off, 64);
                float hi = fmaxf(b1[mi][r], ob1);
                float lo = fminf(b1[mi][r], ob1);
                b2[mi][r] = fmaxf(fmaxf(b2[mi][r], ob2), lo);
                i1[mi][r] = (ob1 > b1[mi][r]) ? oi1 : i1[mi][r];
                b1[mi][r] = hi;
            }
    }

    if (c == 0) {
#pragma unroll
        for (int mi = 0; mi < 2; mi++)
#pragma unroll
            for (int r = 0; r < 4; r++) {
                int rowl = rh * 32 + mi * 16 + quad * 4 + r;
                redb1[ch * 64 + rowl] = b1[mi][r];
                redb2[ch * 64 + rowl] = b2[mi][r];
                redi1[ch * 64 + rowl] = i1[mi][r];
            }
    }
    __syncthreads();

    if (t < 64) {
        float B1 = redb1[t], B2 = redb2[t];
        int I1 = redi1[t];
        float ob1 = redb1[64 + t];
        float ob2 = redb2[64 + t];
        int oi1 = redi1[64 + t];
        float hi = fmaxf(B1, ob1);
        float lo = fminf(B1, ob1);
        B2 = fmaxf(fmaxf(B2, ob2), lo);
        I1 = (ob1 > B1) ? oi1 : I1;
        B1 = hi;
        idx_out[rowbase + t] = I1;
        if (2.0f * (B1 - B2) < MARGIN_F) {
            rpart[rowbase + t] = ~0ull;
            int p = atomicAdd(rcount, 1);
            rlist[p] = rowbase + t;
        }
    }
}

// ---------------------------------------------------------------------------
// Kernel 3: exact fp32 rescue (R16 verified: gll-dbuf + launch_bounds pin).
// ---------------------------------------------------------------------------
#define RR 8        // rows per group (2 per wave)
#define SC 512      // codes per slice
#define CH 64       // codes per staged chunk

__global__ void __launch_bounds__(256, 2)
rescue_kernel(const float* __restrict__ z,
              const float2* __restrict__ emb_t,
              const float* __restrict__ enorm,
              const int* __restrict__ rcount,
              const int* __restrict__ rlist,
              unsigned long long* __restrict__ rpart) {
    __shared__ alignas(16) float2 es[2][64 * 64];   // 2 x 32 KB
    __shared__ float2 ze[RR * 64];                  // 4 KB
    __shared__ int ids[RR];

    const int t = threadIdx.x;
    const int cnt = *rcount;
    if (cnt == 0) return;
    const int ngrp = (cnt + RR - 1) / RR;
    const int nwork = ngrp * 8;

    const int r = t >> 6;                // wave id 0..3; rows r and r+4
    const int cl = t & 63;

    for (int g = blockIdx.x; g < nwork; g += gridDim.x) {
        const int gi = g >> 3;
        const int slice = g & 7;

        if (t < RR) {
            int j = gi * RR + t;
            ids[t] = rlist[j < cnt ? j : cnt - 1];
        }
        __syncthreads();                 // publish ids
        const int rowA = ids[r];
        const int rowB = ids[r + 4];
#pragma unroll
        for (int q2 = 0; q2 < 2; q2++) {
            int i = t + 256 * q2;        // 0..511
            int rr = i >> 6;
            int d2 = i & 63;
            ze[rr * 64 + d2] = ((const float2*)(z + (size_t)ids[rr] * ND))[d2];
        }

        const int kbase = slice * SC;
#pragma unroll
        for (int j = 0; j < 8; j++) {
            int seg = r * 8 + j;         // 0..31
            const float2* src = emb_t + (size_t)(seg * 2 + (cl >> 5)) * NK
                                + kbase + (cl & 31) * 2;
            __builtin_amdgcn_global_load_lds((const unsigned int*)src,
                (unsigned int*)&es[0][seg * 128], 16, 0, 0);
        }
        __syncthreads();                 // drains ze writes + chunk-0 gll

        unsigned long long bestA = ~0ull, bestB = ~0ull;

        for (int ch2 = 0; ch2 < SC / CH; ch2++) {
            const int bi = ch2 & 1;
            if (ch2 < SC / CH - 1) {
                const int kb2 = kbase + (ch2 + 1) * CH;
#pragma unroll
                for (int j = 0; j < 8; j++) {
                    int seg = r * 8 + j;
                    const float2* src = emb_t + (size_t)(seg * 2 + (cl >> 5)) * NK
                                        + kb2 + (cl & 31) * 2;
                    __builtin_amdgcn_global_load_lds((const unsigned int*)src,
                        (unsigned int*)&es[bi ^ 1][seg * 128], 16, 0, 0);
                }
            }

            int k = kbase + ch2 * CH + cl;
            float a0 = 0.f, a1 = 0.f, a2 = 0.f, a3 = 0.f;
            float c0 = 0.f, c1 = 0.f, c2 = 0.f, c3 = 0.f;
#pragma unroll
            for (int d2 = 0; d2 < 64; d2 += 2) {
                float2 ev0 = es[bi][d2 * 64 + cl];       // conflict-free
                float2 ev1 = es[bi][(d2 + 1) * 64 + cl];
                float2 zA0 = ze[r * 64 + d2];            // wave-uniform
                float2 zA1 = ze[r * 64 + d2 + 1];
                float2 zB0 = ze[(r + 4) * 64 + d2];
                float2 zB1 = ze[(r + 4) * 64 + d2 + 1];
                a0 = fmaf(zA0.x, ev0.x, a0);
                a1 = fmaf(zA0.y, ev0.y, a1);
                a2 = fmaf(zA1.x, ev1.x, a2);
                a3 = fmaf(zA1.y, ev1.y, a3);
                c0 = fmaf(zB0.x, ev0.x, c0);
                c1 = fmaf(zB0.y, ev0.y, c1);
                c2 = fmaf(zB1.x, ev1.x, c2);
                c3 = fmaf(zB1.y, ev1.y, c3);
            }
            float sA = fmaf(-2.0f, (a0 + a1) + (a2 + a3), enorm[k]);
            float sB = fmaf(-2.0f, (c0 + c1) + (c2 + c3), enorm[k]);
            unsigned long long pA = pack_si(sA, k);
            unsigned long long pB = pack_si(sB, k);
            bestA = (pA < bestA) ? pA : bestA;
            bestB = (pB < bestB) ? pB : bestB;

            __syncthreads();             // next chunk staged; es[bi] free
        }

        // wave-reduce min for both rows
#pragma unroll
        for (int off = 32; off > 0; off >>= 1) {
            unsigned long long oA = __shfl_down(bestA, off, 64);
            unsigned long long oB = __shfl_down(bestB, off, 64);
            bestA = (oA < bestA) ? oA : bestA;
            bestB = (oB < bestB) ? oB : bestB;
        }
        if (cl == 0) {
            atomicMin(&rpart[rowA], bestA);
            atomicMin(&rpart[rowB], bestB);
        }
    }
}

// ---------------------------------------------------------------------------
// Kernel 4: rescue finalize — unpack winning idx per rescue row.
// ---------------------------------------------------------------------------
__global__ void rescue_fin_kernel(const int* __restrict__ rcount,
                                  const int* __restrict__ rlist,
                                  const unsigned long long* __restrict__ rpart,
                                  int* __restrict__ idx_out) {
    const int cnt = *rcount;
    for (int i = blockIdx.x * blockDim.x + threadIdx.x; i < cnt;
         i += gridDim.x * blockDim.x) {
        int row = rlist[i];
        idx_out[row] = (int)(rpart[row] & 0xffffffffull);
    }
}

// ---------------------------------------------------------------------------
// Kernel 5: gather + loss partial + transposed write. R19: phase-1 loads
// vectorized to float4 (G13 — scalar bf16/fp32 loads are the documented
// 2-2.5x pattern): z read 1KB/instr, emb gather 512B/segment x2, 4x fewer
// issue slots and gather-latency exposures. zq layout (stride 129,
// conflict-free transposed reads) and phase-2 write unchanged.
// ---------------------------------------------------------------------------
__global__ void out_kernel(const float* __restrict__ z,
                           const float* __restrict__ emb,
                           const int* __restrict__ idx,
                           float* __restrict__ out,
                           float* __restrict__ losspart) {
    __shared__ float zq[64 * 129];
    __shared__ int ids[64];
    __shared__ float redl[4];

    const int bid = blockIdx.x;
    const int b = bid >> 6;
    const int h = bid & 63;
    const int rowbase = bid * 64;
    const int t = threadIdx.x;

    if (t < 64) ids[t] = idx[rowbase + t];
    __syncthreads();

    float lsum = 0.f;
    const float4* zg = (const float4*)(z + (size_t)rowbase * ND);
#pragma unroll
    for (int q = 0; q < 8; q++) {
        int i = t + 256 * q;          // 0..2047
        int w = i >> 5;               // row 0..63
        int c4 = i & 31;              // float4 slot 0..31
        float4 zv = zg[w * 32 + c4];
        float4 ev = ((const float4*)(emb + (size_t)ids[w] * ND))[c4];
        float dx = ev.x - zv.x, dy = ev.y - zv.y;
        float dz = ev.z - zv.z, dw = ev.w - zv.w;
        lsum = fmaf(dx, dx, lsum);
        lsum = fmaf(dy, dy, lsum);
        lsum = fmaf(dz, dz, lsum);
        lsum = fmaf(dw, dw, lsum);
        float* dst = &zq[w * 129 + c4 * 4];
        dst[0] = ev.x; dst[1] = ev.y; dst[2] = ev.z; dst[3] = ev.w;
    }
#pragma unroll
    for (int off = 32; off > 0; off >>= 1) lsum += __shfl_down(lsum, off, 64);
    if ((t & 63) == 0) redl[t >> 6] = lsum;
    __syncthreads();
    if (t == 0) losspart[bid] = redl[0] + redl[1] + redl[2] + redl[3];

    const int w = t & 63;
    const int dq = t >> 6;
#pragma unroll
    for (int dd0 = 0; dd0 < 32; dd0++) {
        int dd = dq + 4 * dd0;
        out[(((size_t)b * ND + dd) * NH + h) * NW + w] = zq[w * 129 + dd];
    }
}

// ---------------------------------------------------------------------------
// Kernel 6: final loss reduce
// ---------------------------------------------------------------------------
__global__ void loss_kernel(const float* __restrict__ losspart,
                            float* __restrict__ out) {
    __shared__ float redl[4];
    const int t = threadIdx.x;
    float s = 0.f;
#pragma unroll
    for (int i = 0; i < 4; i++) s += losspart[t + 256 * i];
#pragma unroll
    for (int off = 32; off > 0; off >>= 1) s += __shfl_down(s, off, 64);
    if ((t & 63) == 0) redl[t >> 6] = s;
    __syncthreads();
    if (t == 0) {
        float total = redl[0] + redl[1] + redl[2] + redl[3];
        out[OUT_ELEMS] = 1.25f * total / (float)OUT_ELEMS;
    }
}

// ---------------------------------------------------------------------------
extern "C" void kernel_launch(void* const* d_in, const int* in_sizes, int n_in,
                              void* d_out, int out_size, void* d_ws, size_t ws_size,
                              hipStream_t stream) {
    const float* z = (const float*)d_in[0];      // [16,64,64,128] fp32
    const float* emb = (const float*)d_in[1];    // [4096,128] fp32
    float* out = (float*)d_out;                  // 8388608 + 1 fp32

    char* ws = (char*)d_ws;
    int* ws_idx = (int*)ws;                                         // 256 KB
    float* ws_enorm = (float*)(ws + (256 << 10));                   // 16 KB
    float* ws_losspart = (float*)(ws + (272 << 10));                // 4 KB
    int* ws_rcount = (int*)(ws + (276 << 10));                      // 1 KB
    int* ws_rlist = (int*)(ws + (277 << 10));                       // 256 KB
    unsigned short* ws_eh = (unsigned short*)(ws + (533 << 10));    // 1 MB
    unsigned long long* ws_rpart = (unsigned long long*)(ws + (1557 << 10)); // 512 KB
    float2* ws_embt = (float2*)(ws + (2069 << 10));                 // 2 MB

    hipMemsetAsync(ws_rcount, 0, sizeof(int), stream);
    emb_prep_kernel<<<NK / 4, 256, 0, stream>>>(emb, ws_enorm, ws_eh);
    transp_kernel<<<NK / 64, 256, 0, stream>>>(emb, ws_embt);
    mfma_argmin_kernel<<<NROWS / 64, 256, 0, stream>>>(z, ws_eh, ws_enorm,
                                                       ws_idx, ws_rcount,
                                                       ws_rlist, ws_rpart);
    rescue_kernel<<<2048, 256, 0, stream>>>(z, ws_embt, ws_enorm, ws_rcount,
                                            ws_rlist, ws_rpart);
    rescue_fin_kernel<<<64, 256, 0, stream>>>(ws_rcount, ws_rlist, ws_rpart,
                                              ws_idx);
    out_kernel<<<NB * NH, 256, 0, stream>>>(z, emb, ws_idx, out, ws_losspart);
    loss_kernel<<<1, 256, 0, stream>>>(ws_losspart, out);
}

// Round 21
// 264.386 us; speedup vs baseline: 1.0153x; 1.0153x over previous
//
#include <hip/hip_runtime.h>

// Problem constants
#define NB 16
#define NH 64
#define NW 64
#define ND 128
#define NK 4096
#define NROWS (NB * NH * NW)        // 65536
#define OUT_ELEMS (NB * ND * NH * NW)  // 8388608
// fp16 single-term fast path: score-gap error sigma ~= 0.02; margin 0.10
// ~= 5 sigma. Exact-fp32 rescue handles everything below the margin.
// Ledger: R13 top-3 tracking = 2x argmin (VALU budget ~5 ops/score).
// R14 rescue bound by serialized plain-load staging. R15 dropped
// launch_bounds -> 64-VGPR spill. R16/R18 pin restored: 267.7us.
// R19 out float4: null -> residual not in out phase-1.
// R20: transp fused into prep; argmin addressing diet (advancing gll/en
// pointers + pre-negated ehalf).
#define MARGIN_F 0.10f

typedef _Float16 f16x8 __attribute__((ext_vector_type(8)));
typedef float f32x4 __attribute__((ext_vector_type(4)));

__device__ __forceinline__ unsigned short f2h(float x) {
    _Float16 h = (_Float16)x;              // v_cvt_f16_f32, RNE
    return __builtin_bit_cast(unsigned short, h);
}
// Order-preserving (score,idx) packing: smaller score first, then smaller idx.
__device__ __forceinline__ unsigned long long pack_si(float s, int idx) {
    unsigned int u = __float_as_uint(s);
    unsigned int key = ((int)u < 0) ? ~u : (u | 0x80000000u);
    return ((unsigned long long)key << 32) | (unsigned int)idx;
}

// ---------------------------------------------------------------------------
// Kernel 1: emb prep — enorm (fp32 exact), ehalf = -0.5*enorm (argmin's
// acc-init constant, hoisted out of the hot loop), fp16 codebook e_h in the
// SWIZZLED layout (dim ^ ((code&7)<<3)), AND the transposed fp32 codebook
// emb_t[d2][code] (was a separate 64-block kernel; fused here via a 2KB LDS
// tile for full 1024-block parallelism + one fewer launch).
// ---------------------------------------------------------------------------
__global__ void emb_prep_kernel(const float* __restrict__ emb,
                                float* __restrict__ enorm,
                                float* __restrict__ ehalf,
                                unsigned short* __restrict__ e_h,
                                float2* __restrict__ emb_t) {
    __shared__ float tile4[4][ND];     // 2 KB: this block's 4 codebook rows
    const int t = threadIdx.x;
    const int wid = t >> 6;
    const int lane = t & 63;
    const int code = blockIdx.x * 4 + wid;

    const float* e = emb + (size_t)code * ND;
    float a = e[lane];
    float b = e[lane + 64];
    const int m = (code & 7) << 3;
    e_h[(size_t)code * ND + (lane ^ m)] = f2h(a);
    e_h[(size_t)code * ND + ((lane + 64) ^ m)] = f2h(b);
    tile4[wid][lane] = a;
    tile4[wid][lane + 64] = b;
    float s = a * a + b * b;
#pragma unroll
    for (int off = 32; off > 0; off >>= 1) s += __shfl_down(s, off, 64);
    if (lane == 0) {
        enorm[code] = s;
        ehalf[code] = -0.5f * s;
    }
    __syncthreads();
    // transpose write: thread -> (d2 = t>>2, cw = t&3); 4 consecutive codes
    // per d2 give 32B-contiguous float2 stores.
    const int d2 = t >> 2;
    const int cw = t & 3;
    emb_t[(size_t)d2 * NK + blockIdx.x * 4 + cw] =
        make_float2(tile4[cw][2 * d2], tile4[cw][2 * d2 + 1]);
}

// ---------------------------------------------------------------------------
// Kernel 2: MFMA argmin (R11 structure; R20 addressing diet).
// Max-form q = z.e - 0.5*en via acc-init fold (h loaded pre-negated from
// ehalf); branch-free top-2 (5 ops/score). gll source = advancing per-thread
// pointer (one 64-bit add/step; j*512 folds into the 13-bit imm offset);
// enorm pipeline likewise via advancing pointer.
// ---------------------------------------------------------------------------
#define ZST 136   // z staging row stride in ushort (272 B)

__global__ void
__attribute__((amdgpu_flat_work_group_size(256, 256)))
mfma_argmin_kernel(const float* __restrict__ z,
                   const unsigned short* __restrict__ e_h,
                   const float* __restrict__ ehalf,
                   int* __restrict__ idx_out,
                   int* __restrict__ rcount,
                   int* __restrict__ rlist,
                   unsigned long long* __restrict__ rpart) {
    __shared__ alignas(16) unsigned short ubuf[2 * 64 * ND];   // 32768 B
    __shared__ float redb1[2 * 64];
    __shared__ float redb2[2 * 64];
    __shared__ int   redi1[2 * 64];

    const int bid = blockIdx.x;
    const int rowbase = bid * 64;
    const int t = threadIdx.x;
    const int lane = t & 63;
    const int wid = __builtin_amdgcn_readfirstlane(t >> 6);

    const float4* zg = (const float4*)(z + (size_t)rowbase * ND);
#pragma unroll
    for (int q = 0; q < 8; q++) {
        int i = t + 256 * q;               // 0..2047
        float4 v = zg[i];
        int r = i >> 5;
        int c4 = (i & 31) << 2;
        ushort4 hv = make_ushort4(f2h(v.x), f2h(v.y), f2h(v.z), f2h(v.w));
        *(ushort4*)&ubuf[r * ZST + c4] = hv;
    }
    __syncthreads();

    const int quad = lane >> 4;
    const int c = lane & 15;
    const int rh = wid >> 1;               // row half
    const int ch = wid & 1;                // code half

    f16x8 ar[2][4];
#pragma unroll
    for (int mi = 0; mi < 2; mi++)
#pragma unroll
        for (int kk = 0; kk < 4; kk++)
            ar[mi][kk] = *(const f16x8*)&ubuf[(rh * 32 + mi * 16 + c) * ZST + quad * 8 + kk * 32];
    __syncthreads();

    // advancing per-thread staging pointer: base covers this wave's 4 segs
    // (j*512 ushorts = 1-3 KB folds into the gll instruction offset).
    const unsigned short* gsrc = e_h + (size_t)(wid << 2) * 512 + lane * 8;
#pragma unroll
    for (int j = 0; j < 4; j++)
        __builtin_amdgcn_global_load_lds(
            (const unsigned int*)(gsrc + j * 512),
            (unsigned int*)&ubuf[((wid << 2) + j) * 512], 16, 0, 0);

    const float* pen = ehalf + ch * 32 + c;    // advancing enorm pointer
    float en0 = pen[0];
    float en1 = pen[16];
    __syncthreads();

    const int bswz = (c & 7) << 3;
    const int bbase0 = (ch * 32 + c) * ND;

    float b1[2][4], b2[2][4];
    int i1[2][4];
#pragma unroll
    for (int mi = 0; mi < 2; mi++)
#pragma unroll
        for (int r = 0; r < 4; r++) { b1[mi][r] = -3.4e38f; b2[mi][r] = -3.4e38f; i1[mi][r] = 0; }

    for (int ts = 0; ts < NK / 64; ts++) {
        const int cur = ts & 1;
        const int curoff = cur << 13;

        float nen0 = 0.f, nen1 = 0.f;
        if (ts < NK / 64 - 1) {
            nen0 = pen[64];
            nen1 = pen[80];
            gsrc += 64 * ND;               // one 64-bit add per step
#pragma unroll
            for (int j = 0; j < 4; j++)
                __builtin_amdgcn_global_load_lds(
                    (const unsigned int*)(gsrc + j * 512),
                    (unsigned int*)&ubuf[(curoff ^ 8192) + ((wid << 2) + j) * 512], 16, 0, 0);
        }

        // acc init = ehalf (pre-negated)  ->  MFMA output q = z.e - 0.5*en
        f32x4 acc[2][2];
#pragma unroll
        for (int mi = 0; mi < 2; mi++) {
            acc[mi][0] = (f32x4){en0, en0, en0, en0};
            acc[mi][1] = (f32x4){en1, en1, en1, en1};
        }

#pragma unroll
        for (int kk = 0; kk < 4; kk++) {
            const int doff = (quad * 8 + kk * 32) ^ bswz;
            f16x8 bv0 = *(const f16x8*)&ubuf[curoff + bbase0 + doff];
            f16x8 bv1 = *(const f16x8*)&ubuf[curoff + bbase0 + 16 * ND + doff];
            acc[0][0] = __builtin_amdgcn_mfma_f32_16x16x32_f16(ar[0][kk], bv0, acc[0][0], 0, 0, 0);
            acc[0][1] = __builtin_amdgcn_mfma_f32_16x16x32_f16(ar[0][kk], bv1, acc[0][1], 0, 0, 0);
            acc[1][0] = __builtin_amdgcn_mfma_f32_16x16x32_f16(ar[1][kk], bv0, acc[1][0], 0, 0, 0);
            acc[1][1] = __builtin_amdgcn_mfma_f32_16x16x32_f16(ar[1][kk], bv1, acc[1][1], 0, 0, 0);
        }

#pragma unroll
        for (int ni = 0; ni < 2; ni++) {
            const int n = ts * 64 + ch * 32 + ni * 16 + c;
#pragma unroll
            for (int mi = 0; mi < 2; mi++)
#pragma unroll
                for (int r = 0; r < 4; r++) {
                    float q = acc[mi][ni][r];
                    b2[mi][r] = fmaxf(b2[mi][r], fminf(b1[mi][r], q));
                    i1[mi][r] = (q > b1[mi][r]) ? n : i1[mi][r];
                    b1[mi][r] = fmaxf(b1[mi][r], q);
                }
        }

        __syncthreads();
        en0 = nen0;
        en1 = nen1;
        pen += 64;
    }

#pragma unroll
    for (int off = 1; off < 16; off <<= 1) {
#pragma unroll
        for (int mi = 0; mi < 2; mi++)
#pragma unroll
            for (int r = 0; r < 4; r++) {
                float ob1 = __shfl_xor(b1[mi][r], off, 64);
                float ob2 = __shfl_xor(b2[mi][r], off, 64);
                int oi1 = __shfl_xor(i1[mi][r], off, 64);
                float hi = fmaxf(b1[mi][r], ob1);
                float lo = fminf(b1[mi][r], ob1);
                b2[mi][r] = fmaxf(fmaxf(b2[mi][r], ob2), lo);
                i1[mi][r] = (ob1 > b1[mi][r]) ? oi1 : i1[mi][r];
                b1[mi][r] = hi;
            }
    }

    if (c == 0) {
#pragma unroll
        for (int mi = 0; mi < 2; mi++)
#pragma unroll
            for (int r = 0; r < 4; r++) {
                int rowl = rh * 32 + mi * 16 + quad * 4 + r;
                redb1[ch * 64 + rowl] = b1[mi][r];
                redb2[ch * 64 + rowl] = b2[mi][r];
                redi1[ch * 64 + rowl] = i1[mi][r];
            }
    }
    __syncthreads();

    if (t < 64) {
        float B1 = redb1[t], B2 = redb2[t];
        int I1 = redi1[t];
        float ob1 = redb1[64 + t];
        float ob2 = redb2[64 + t];
        int oi1 = redi1[64 + t];
        float hi = fmaxf(B1, ob1);
        float lo = fminf(B1, ob1);
        B2 = fmaxf(fmaxf(B2, ob2), lo);
        I1 = (ob1 > B1) ? oi1 : I1;
        B1 = hi;
        idx_out[rowbase + t] = I1;
        if (2.0f * (B1 - B2) < MARGIN_F) {
            rpart[rowbase + t] = ~0ull;
            int p = atomicAdd(rcount, 1);
            rlist[p] = rowbase + t;
        }
    }
}

// ---------------------------------------------------------------------------
// Kernel 3: exact fp32 rescue (R16 verified: gll-dbuf + launch_bounds pin).
// ---------------------------------------------------------------------------
#define RR 8        // rows per group (2 per wave)
#define SC 512      // codes per slice
#define CH 64       // codes per staged chunk

__global__ void __launch_bounds__(256, 2)
rescue_kernel(const float* __restrict__ z,
              const float2* __restrict__ emb_t,
              const float* __restrict__ enorm,
              const int* __restrict__ rcount,
              const int* __restrict__ rlist,
              unsigned long long* __restrict__ rpart) {
    __shared__ alignas(16) float2 es[2][64 * 64];   // 2 x 32 KB
    __shared__ float2 ze[RR * 64];                  // 4 KB
    __shared__ int ids[RR];

    const int t = threadIdx.x;
    const int cnt = *rcount;
    if (cnt == 0) return;
    const int ngrp = (cnt + RR - 1) / RR;
    const int nwork = ngrp * 8;

    const int r = t >> 6;                // wave id 0..3; rows r and r+4
    const int cl = t & 63;

    for (int g = blockIdx.x; g < nwork; g += gridDim.x) {
        const int gi = g >> 3;
        const int slice = g & 7;

        if (t < RR) {
            int j = gi * RR + t;
            ids[t] = rlist[j < cnt ? j : cnt - 1];
        }
        __syncthreads();                 // publish ids
        const int rowA = ids[r];
        const int rowB = ids[r + 4];
#pragma unroll
        for (int q2 = 0; q2 < 2; q2++) {
            int i = t + 256 * q2;        // 0..511
            int rr = i >> 6;
            int d2 = i & 63;
            ze[rr * 64 + d2] = ((const float2*)(z + (size_t)ids[rr] * ND))[d2];
        }

        const int kbase = slice * SC;
#pragma unroll
        for (int j = 0; j < 8; j++) {
            int seg = r * 8 + j;         // 0..31
            const float2* src = emb_t + (size_t)(seg * 2 + (cl >> 5)) * NK
                                + kbase + (cl & 31) * 2;
            __builtin_amdgcn_global_load_lds((const unsigned int*)src,
                (unsigned int*)&es[0][seg * 128], 16, 0, 0);
        }
        __syncthreads();                 // drains ze writes + chunk-0 gll

        unsigned long long bestA = ~0ull, bestB = ~0ull;

        for (int ch2 = 0; ch2 < SC / CH; ch2++) {
            const int bi = ch2 & 1;
            if (ch2 < SC / CH - 1) {
                const int kb2 = kbase + (ch2 + 1) * CH;
#pragma unroll
                for (int j = 0; j < 8; j++) {
                    int seg = r * 8 + j;
                    const float2* src = emb_t + (size_t)(seg * 2 + (cl >> 5)) * NK
                                        + kb2 + (cl & 31) * 2;
                    __builtin_amdgcn_global_load_lds((const unsigned int*)src,
                        (unsigned int*)&es[bi ^ 1][seg * 128], 16, 0, 0);
                }
            }

            int k = kbase + ch2 * CH + cl;
            float a0 = 0.f, a1 = 0.f, a2 = 0.f, a3 = 0.f;
            float c0 = 0.f, c1 = 0.f, c2 = 0.f, c3 = 0.f;
#pragma unroll
            for (int d2 = 0; d2 < 64; d2 += 2) {
                float2 ev0 = es[bi][d2 * 64 + cl];       // conflict-free
                float2 ev1 = es[bi][(d2 + 1) * 64 + cl];
                float2 zA0 = ze[r * 64 + d2];            // wave-uniform
                float2 zA1 = ze[r * 64 + d2 + 1];
                float2 zB0 = ze[(r + 4) * 64 + d2];
                float2 zB1 = ze[(r + 4) * 64 + d2 + 1];
                a0 = fmaf(zA0.x, ev0.x, a0);
                a1 = fmaf(zA0.y, ev0.y, a1);
                a2 = fmaf(zA1.x, ev1.x, a2);
                a3 = fmaf(zA1.y, ev1.y, a3);
                c0 = fmaf(zB0.x, ev0.x, c0);
                c1 = fmaf(zB0.y, ev0.y, c1);
                c2 = fmaf(zB1.x, ev1.x, c2);
                c3 = fmaf(zB1.y, ev1.y, c3);
            }
            float sA = fmaf(-2.0f, (a0 + a1) + (a2 + a3), enorm[k]);
            float sB = fmaf(-2.0f, (c0 + c1) + (c2 + c3), enorm[k]);
            unsigned long long pA = pack_si(sA, k);
            unsigned long long pB = pack_si(sB, k);
            bestA = (pA < bestA) ? pA : bestA;
            bestB = (pB < bestB) ? pB : bestB;

            __syncthreads();             // next chunk staged; es[bi] free
        }

        // wave-reduce min for both rows
#pragma unroll
        for (int off = 32; off > 0; off >>= 1) {
            unsigned long long oA = __shfl_down(bestA, off, 64);
            unsigned long long oB = __shfl_down(bestB, off, 64);
            bestA = (oA < bestA) ? oA : bestA;
            bestB = (oB < bestB) ? oB : bestB;
        }
        if (cl == 0) {
            atomicMin(&rpart[rowA], bestA);
            atomicMin(&rpart[rowB], bestB);
        }
    }
}

// ---------------------------------------------------------------------------
// Kernel 4: rescue finalize — unpack winning idx per rescue row.
// ---------------------------------------------------------------------------
__global__ void rescue_fin_kernel(const int* __restrict__ rcount,
                                  const int* __restrict__ rlist,
                                  const unsigned long long* __restrict__ rpart,
                                  int* __restrict__ idx_out) {
    const int cnt = *rcount;
    for (int i = blockIdx.x * blockDim.x + threadIdx.x; i < cnt;
         i += gridDim.x * blockDim.x) {
        int row = rlist[i];
        idx_out[row] = (int)(rpart[row] & 0xffffffffull);
    }
}

// ---------------------------------------------------------------------------
// Kernel 5: gather + loss partial + transposed write (R19 float4 phase-1).
// ---------------------------------------------------------------------------
__global__ void out_kernel(const float* __restrict__ z,
                           const float* __restrict__ emb,
                           const int* __restrict__ idx,
                           float* __restrict__ out,
                           float* __restrict__ losspart) {
    __shared__ float zq[64 * 129];
    __shared__ int ids[64];
    __shared__ float redl[4];

    const int bid = blockIdx.x;
    const int b = bid >> 6;
    const int h = bid & 63;
    const int rowbase = bid * 64;
    const int t = threadIdx.x;

    if (t < 64) ids[t] = idx[rowbase + t];
    __syncthreads();

    float lsum = 0.f;
    const float4* zg = (const float4*)(z + (size_t)rowbase * ND);
#pragma unroll
    for (int q = 0; q < 8; q++) {
        int i = t + 256 * q;          // 0..2047
        int w = i >> 5;               // row 0..63
        int c4 = i & 31;              // float4 slot 0..31
        float4 zv = zg[w * 32 + c4];
        float4 ev = ((const float4*)(emb + (size_t)ids[w] * ND))[c4];
        float dx = ev.x - zv.x, dy = ev.y - zv.y;
        float dz = ev.z - zv.z, dw = ev.w - zv.w;
        lsum = fmaf(dx, dx, lsum);
        lsum = fmaf(dy, dy, lsum);
        lsum = fmaf(dz, dz, lsum);
        lsum = fmaf(dw, dw, lsum);
        float* dst = &zq[w * 129 + c4 * 4];
        dst[0] = ev.x; dst[1] = ev.y; dst[2] = ev.z; dst[3] = ev.w;
    }
#pragma unroll
    for (int off = 32; off > 0; off >>= 1) lsum += __shfl_down(lsum, off, 64);
    if ((t & 63) == 0) redl[t >> 6] = lsum;
    __syncthreads();
    if (t == 0) losspart[bid] = redl[0] + redl[1] + redl[2] + redl[3];

    const int w = t & 63;
    const int dq = t >> 6;
#pragma unroll
    for (int dd0 = 0; dd0 < 32; dd0++) {
        int dd = dq + 4 * dd0;
        out[(((size_t)b * ND + dd) * NH + h) * NW + w] = zq[w * 129 + dd];
    }
}

// ---------------------------------------------------------------------------
// Kernel 6: final loss reduce
// ---------------------------------------------------------------------------
__global__ void loss_kernel(const float* __restrict__ losspart,
                            float* __restrict__ out) {
    __shared__ float redl[4];
    const int t = threadIdx.x;
    float s = 0.f;
#pragma unroll
    for (int i = 0; i < 4; i++) s += losspart[t + 256 * i];
#pragma unroll
    for (int off = 32; off > 0; off >>= 1) s += __shfl_down(s, off, 64);
    if ((t & 63) == 0) redl[t >> 6] = s;
    __syncthreads();
    if (t == 0) {
        float total = redl[0] + redl[1] + redl[2] + redl[3];
        out[OUT_ELEMS] = 1.25f * total / (float)OUT_ELEMS;
    }
}

// ---------------------------------------------------------------------------
extern "C" void kernel_launch(void* const* d_in, const int* in_sizes, int n_in,
                              void* d_out, int out_size, void* d_ws, size_t ws_size,
                              hipStream_t stream) {
    const float* z = (const float*)d_in[0];      // [16,64,64,128] fp32
    const float* emb = (const float*)d_in[1];    // [4096,128] fp32
    float* out = (float*)d_out;                  // 8388608 + 1 fp32

    char* ws = (char*)d_ws;
    int* ws_idx = (int*)ws;                                         // 256 KB
    float* ws_enorm = (float*)(ws + (256 << 10));                   // 16 KB
    float* ws_losspart = (float*)(ws + (272 << 10));                // 4 KB
    int* ws_rcount = (int*)(ws + (276 << 10));                      // 1 KB
    int* ws_rlist = (int*)(ws + (277 << 10));                       // 256 KB
    unsigned short* ws_eh = (unsigned short*)(ws + (533 << 10));    // 1 MB
    unsigned long long* ws_rpart = (unsigned long long*)(ws + (1557 << 10)); // 512 KB
    float2* ws_embt = (float2*)(ws + (2069 << 10));                 // 2 MB
    float* ws_ehalf = (float*)(ws + (4117 << 10));                  // 16 KB

    hipMemsetAsync(ws_rcount, 0, sizeof(int), stream);
    emb_prep_kernel<<<NK / 4, 256, 0, stream>>>(emb, ws_enorm, ws_ehalf,
                                                ws_eh, ws_embt);
    mfma_argmin_kernel<<<NROWS / 64, 256, 0, stream>>>(z, ws_eh, ws_ehalf,
                                                       ws_idx, ws_rcount,
                                                       ws_rlist, ws_rpart);
    rescue_kernel<<<2048, 256, 0, stream>>>(z, ws_embt, ws_enorm, ws_rcount,
                                            ws_rlist, ws_rpart);
    rescue_fin_kernel<<<64, 256, 0, stream>>>(ws_rcount, ws_rlist, ws_rpart,
                                              ws_idx);
    out_kernel<<<NB * NH, 256, 0, stream>>>(z, emb, ws_idx, out, ws_losspart);
    loss_kernel<<<1, 256, 0, stream>>>(ws_losspart, out);
}